// Round 7
// baseline (272.348 us; speedup 1.0000x reference)
//
#include <hip/hip_runtime.h>
#include <stdint.h>

#define L2E 1.44269504088896340736f

typedef _Float16 half8 __attribute__((ext_vector_type(8)));
typedef float floatx4 __attribute__((ext_vector_type(4)));
typedef float floatx16 __attribute__((ext_vector_type(16)));

static __device__ __forceinline__ unsigned short f32_to_f16u(float f) {
  union { _Float16 h; unsigned short s; } cv; cv.h = (_Float16)f; return cv.s;
}
static __device__ __forceinline__ _Float16 f32h(float f) { return (_Float16)f; }

// ---------------------------------------------------------------------------
// Projection GEMM: outT[n][o] = sum_c X[c][n]*W[o][c] + b[o]; 64n x 64o per block.
// X tile staged to LDS as fp16 [256 c][pitch 74] (coalesced float4 row loads)
// -> A-frags become 8x ds_read_u16 (2-way bank = free) instead of 64 strided
// global loads. W staged as before (b128 frags).
// z=0: q,k from depth -> qT,kT [b][n][32]; z=1..4: v quarter from rgb.
// ---------------------------------------------------------------------------
__global__ __launch_bounds__(256, 2) void proj_kernel(
    const float* __restrict__ rgb,
    const float* __restrict__ depth,
    const float* __restrict__ Wq, const float* __restrict__ bq,
    const float* __restrict__ Wk, const float* __restrict__ bk,
    const float* __restrict__ Wv, const float* __restrict__ bv,
    unsigned short* __restrict__ qT,
    unsigned short* __restrict__ kT,
    unsigned short* __restrict__ v)
{
  __shared__ __align__(16) unsigned short sW[64 * 256];   // 32 KB, swizzled
  __shared__ __align__(16) unsigned short sX[256 * 74];   // 37.9 KB, [c][pitch 74]

  const int n0 = blockIdx.x * 64;
  const int b  = blockIdx.y;
  const int z  = blockIdx.z;
  const int t  = threadIdx.x;
  const int w  = t >> 6;
  const int lane = t & 63;
  const int l15 = lane & 15;
  const int q4  = lane >> 4;
  const int nl  = 16 * w + l15;  // local n row for A-frag

  const float* X = (z == 0) ? depth : rgb;
  const float* xb = X + (size_t)b * 256 * 4096 + n0;
  const int colbase = (z == 0) ? 0 : (z - 1) * 64;

  // stage W [64 o][256 c] fp16, 16B-chunk swizzle by (og&7)
#pragma unroll
  for (int it = 0; it < 8; it++) {
    int L = it * 256 + t;
    int og = L >> 5;
    int phys = L & 31;
    int ci = phys ^ (og & 7);
    const float* wr;
    if (z == 0) wr = (og < 32) ? (Wq + (size_t)og * 256) : (Wk + (size_t)(og - 32) * 256);
    else        wr = Wv + (size_t)(colbase + og) * 256;
    float4 w0 = *(const float4*)(wr + ci * 8);
    float4 w1 = *(const float4*)(wr + ci * 8 + 4);
    half8 h;
    h[0] = f32h(w0.x); h[1] = f32h(w0.y); h[2] = f32h(w0.z); h[3] = f32h(w0.w);
    h[4] = f32h(w1.x); h[5] = f32h(w1.y); h[6] = f32h(w1.z); h[7] = f32h(w1.w);
    *(half8*)&sW[(size_t)L * 8] = h;
  }

  // stage X tile [256 c][64 n] -> fp16 LDS (coalesced float4 per 16-lane group)
#pragma unroll
  for (int it = 0; it < 16; it++) {
    int c = it * 16 + (t >> 4);
    int nc = 4 * (t & 15);
    float4 x4 = *(const float4*)&xb[(size_t)c * 4096 + nc];
    ushort4 st;
    st.x = f32_to_f16u(x4.x); st.y = f32_to_f16u(x4.y);
    st.z = f32_to_f16u(x4.z); st.w = f32_to_f16u(x4.w);
    *(ushort4*)&sX[c * 74 + nc] = st;
  }

  float bias[4];
#pragma unroll
  for (int ct = 0; ct < 4; ct++) {
    int og = ct * 16 + l15;
    if (z == 0) bias[ct] = (og < 32) ? bq[og] : bk[og - 32];
    else        bias[ct] = bv[colbase + og];
  }
  __syncthreads();

  floatx4 acc[4];
#pragma unroll
  for (int i = 0; i < 4; i++) acc[i] = (floatx4){0.f, 0.f, 0.f, 0.f};

  const _Float16* sXh = (const _Float16*)sX;
#pragma unroll
  for (int ks = 0; ks < 8; ks++) {
    half8 a;
#pragma unroll
    for (int j = 0; j < 8; j++)
      a[j] = sXh[(ks * 32 + q4 * 8 + j) * 74 + nl];
    const int ci = ks * 4 + q4;
#pragma unroll
    for (int ct = 0; ct < 4; ct++) {
      int og = ct * 16 + l15;
      half8 bf = *(const half8*)&sW[og * 256 + ((ci ^ (og & 7)) * 8)];
      acc[ct] = __builtin_amdgcn_mfma_f32_16x16x32_f16(a, bf, acc[ct], 0, 0, 0);
    }
  }

  __syncthreads();  // sW/sX reads done before reuse

  if (z == 0) {
#pragma unroll
    for (int ct = 0; ct < 4; ct++) {
      int og = ct * 16 + l15;
#pragma unroll
      for (int r = 0; r < 4; r++) {
        int n = n0 + 16 * w + q4 * 4 + r;
        unsigned short hv = f32_to_f16u(acc[ct][r] + bias[ct]);
        if (og < 32) qT[((size_t)b * 4096 + n) * 32 + og] = hv;
        else         kT[((size_t)b * 4096 + n) * 32 + (og - 32)] = hv;
      }
    }
  } else {
    unsigned short* tile = sW;  // reuse: [64 co][pitch 72]
#pragma unroll
    for (int ct = 0; ct < 4; ct++) {
#pragma unroll
      for (int r = 0; r < 4; r++) {
        int co_l = ct * 16 + l15;
        int nn = 16 * w + q4 * 4 + r;
        tile[co_l * 72 + nn] = f32_to_f16u(acc[ct][r] + bias[ct]);
      }
    }
    __syncthreads();
#pragma unroll
    for (int it = 0; it < 2; it++) {
      int co_l = it * 32 + (t >> 3);
      int ch = t & 7;
      int4 val = *(const int4*)&tile[co_l * 72 + ch * 8];
      *(int4*)&v[((size_t)b * 256 + colbase + co_l) * 4096 + n0 + ch * 8] = val;
    }
  }
}

// ---------------------------------------------------------------------------
// Flash attention, split-m, co-split PV (R5 structure) + global->reg prefetch:
// V/K loads for iter i+1 issued right after barrier B of iter i, hidden under
// S + softmax + PV compute; barrier A's vmcnt drain becomes ~free.
// ---------------------------------------------------------------------------
__global__ __launch_bounds__(256, 4) void attn_kernel(
    const unsigned short* __restrict__ qT,  // [b][n][32] fp16
    const unsigned short* __restrict__ kT,  // [b][m][32] fp16
    const unsigned short* __restrict__ v,   // [b][co][m] fp16
    unsigned short* __restrict__ Op,        // [chunk][b][co][n] fp16 unnormalized
    float* __restrict__ lW)                 // [chunk][b][n]
{
  __shared__ __align__(16) unsigned char smem[36864];
  unsigned short* sV = (unsigned short*)smem;              // [256co][32m] swizzled (16384 B)
  unsigned short* sK = (unsigned short*)(smem + 16384);    // [32m][32c] swizzled (2048 B)
  unsigned short* sP = (unsigned short*)(smem + 18432);    // [64n][pitch 42] (5376 B)

  const int n0 = blockIdx.x * 64;
  const int b  = blockIdx.y;
  const int chunk = blockIdx.z;
  const int t  = threadIdx.x;
  const int w  = t >> 6;
  const int lane = t & 63;
  const int l15 = lane & 15;
  const int q4  = lane >> 4;
  const int l31 = lane & 31;
  const int hi  = lane >> 5;

  const unsigned short* qrow = qT + ((size_t)b * 4096 + n0 + 16 * w + l15) * 32 + q4 * 8;
  half8 aq = *(const half8*)qrow;

  const unsigned short* vB = v  + (size_t)b * 256 * 4096;
  const unsigned short* kB = kT + (size_t)b * 4096 * 32;

  float lsum[4] = {0.f, 0.f, 0.f, 0.f};
  floatx16 acc[2][2];
#pragma unroll
  for (int nt = 0; nt < 2; nt++)
#pragma unroll
    for (int ct = 0; ct < 2; ct++)
#pragma unroll
      for (int i = 0; i < 16; i++) acc[nt][ct][i] = 0.f;
  const floatx4 zf = (floatx4){0.f, 0.f, 0.f, 0.f};

  const int mbase = chunk * 1024;

  // V-staging address components (constant across iters)
  const int svc = (4 * 256 > 0) ? 0 : 0;
  uint4 pv[4];
  uint4 pk;
  // prefetch iter 0
#pragma unroll
  for (int j = 0; j < 4; j++) {
    int lin = j * 256 + t;
    int c = lin >> 2;
    int p = lin & 3;
    int lc = p ^ ((c >> 1) & 3);
    pv[j] = *(const uint4*)&vB[(size_t)c * 4096 + mbase + lc * 8];
  }
  if (t < 128) {
    int m = t >> 2, p = t & 3, lc = p ^ ((m >> 1) & 3);
    pk = *(const uint4*)&kB[(size_t)(mbase + m) * 32 + lc * 8];
  }
  (void)svc;

  for (int mi = 0; mi < 1024; mi += 32) {
    __syncthreads();  // A: prev PV reads done; drains vmcnt for prefetched regs
    // commit staged tiles from registers
#pragma unroll
    for (int j = 0; j < 4; j++)
      *(uint4*)&sV[(j * 256 + t) * 8] = pv[j];
    if (t < 128)
      *(uint4*)&sK[t * 8] = pk;
    __syncthreads();  // B: tiles visible

    // issue next-iter global loads (hidden under compute below)
    if (mi < 992) {
      const int m0n = mbase + mi + 32;
#pragma unroll
      for (int j = 0; j < 4; j++) {
        int lin = j * 256 + t;
        int c = lin >> 2;
        int p = lin & 3;
        int lc = p ^ ((c >> 1) & 3);
        pv[j] = *(const uint4*)&vB[(size_t)c * 4096 + m0n + lc * 8];
      }
      if (t < 128) {
        int m = t >> 2, p = t & 3, lc = p ^ ((m >> 1) & 3);
        pk = *(const uint4*)&kB[(size_t)(m0n + m) * 32 + lc * 8];
      }
    }

    // S phase: wave w computes rows 16w..16w+15
    half8 bk0 = *(const half8*)&sK[l15 * 32 + ((q4 ^ ((l15 >> 1) & 3)) * 8)];
    half8 bk1 = *(const half8*)&sK[(16 + l15) * 32 + ((q4 ^ (((16 + l15) >> 1) & 3)) * 8)];
    floatx4 s0 = __builtin_amdgcn_mfma_f32_16x16x32_f16(aq, bk0, zf, 0, 0, 0);
    floatx4 s1 = __builtin_amdgcn_mfma_f32_16x16x32_f16(aq, bk1, zf, 0, 0, 0);

    float p0[4], p1[4];
#pragma unroll
    for (int r = 0; r < 4; r++) {
      p0[r] = exp2f(s0[r] * L2E);
      p1[r] = exp2f(s1[r] * L2E);
      lsum[r] += p0[r] + p1[r];
    }
#pragma unroll
    for (int r = 0; r < 4; r++) {
      int row = w * 16 + q4 * 4 + r;
      sP[row * 42 + l15]      = f32_to_f16u(p0[r]);
      sP[row * 42 + 16 + l15] = f32_to_f16u(p1[r]);
    }
    __syncthreads();  // C: P visible to all waves

    // PV phase: wave w covers co = w*64 .. w*64+63, all 64 n
#pragma unroll
    for (int kst = 0; kst < 2; kst++) {
      half8 bvv[2];
#pragma unroll
      for (int ct = 0; ct < 2; ct++) {
        int co = w * 64 + ct * 32 + l31;
        int lc = (kst * 2 + hi) ^ ((co >> 1) & 3);
        bvv[ct] = *(const half8*)&sV[(co * 4 + lc) * 8];
      }
#pragma unroll
      for (int nt = 0; nt < 2; nt++) {
        half8 ap = *(const half8*)&sP[(nt * 32 + l31) * 42 + kst * 16 + hi * 8];
#pragma unroll
        for (int ct = 0; ct < 2; ct++) {
          acc[nt][ct] = __builtin_amdgcn_mfma_f32_32x32x16_f16(ap, bvv[ct], acc[nt][ct], 0, 0, 0);
        }
      }
    }
  }

  // l reduction over the 16 lanes of each row group
#pragma unroll
  for (int off = 1; off < 16; off <<= 1) {
#pragma unroll
    for (int r = 0; r < 4; r++) lsum[r] += __shfl_xor(lsum[r], off);
  }
  if (l15 == 0) {
#pragma unroll
    for (int r = 0; r < 4; r++)
      lW[((size_t)chunk * 4 + b) * 4096 + n0 + 16 * w + q4 * 4 + r] = lsum[r];
  }

  // epilogue: single-pass LDS transpose [256 co][pitch 72] fp16 = 36864 B
  __syncthreads();
  unsigned short* sO = (unsigned short*)smem;
#pragma unroll
  for (int nt = 0; nt < 2; nt++) {
#pragma unroll
    for (int ct = 0; ct < 2; ct++) {
      int co_l = w * 64 + ct * 32 + l31;
#pragma unroll
      for (int g = 0; g < 4; g++) {
        int nn = nt * 32 + g * 8 + hi * 4;
        ushort4 pkk;
        pkk.x = f32_to_f16u(acc[nt][ct][g * 4 + 0]);
        pkk.y = f32_to_f16u(acc[nt][ct][g * 4 + 1]);
        pkk.z = f32_to_f16u(acc[nt][ct][g * 4 + 2]);
        pkk.w = f32_to_f16u(acc[nt][ct][g * 4 + 3]);
        *(ushort4*)&sO[co_l * 72 + nn] = pkk;
      }
    }
  }
  __syncthreads();
#pragma unroll
  for (int s = 0; s < 8; s++) {
    int co_l = s * 32 + (t >> 3);
    int ch = t & 7;
    int4 val = *(const int4*)&sO[co_l * 72 + ch * 8];
    *(int4*)&Op[(((size_t)chunk * 4 + b) * 256 + co_l) * 4096 + n0 + ch * 8] = val;
  }
}

// ---------------------------------------------------------------------------
// Combine: out[b][co][n] = sum_ch Op[ch][b][co][n] / sum_ch lW[ch][b][n]
// 2048 blocks: one co per block-z.
// ---------------------------------------------------------------------------
__global__ __launch_bounds__(256) void combine_kernel(
    const unsigned short* __restrict__ Op,
    const float* __restrict__ lW,
    float* __restrict__ out)
{
  const int t = threadIdx.x;
  const int b = blockIdx.y;
  const int co = blockIdx.z;
  const size_t n8 = (size_t)blockIdx.x * 2048 + (size_t)t * 8;

  float sum[8] = {0.f, 0.f, 0.f, 0.f, 0.f, 0.f, 0.f, 0.f};
  float o[8]   = {0.f, 0.f, 0.f, 0.f, 0.f, 0.f, 0.f, 0.f};
#pragma unroll
  for (int ch = 0; ch < 4; ch++) {
    const float* lp = lW + ((size_t)ch * 4 + b) * 4096 + n8;
    float4 a0 = *(const float4*)lp;
    float4 a1 = *(const float4*)(lp + 4);
    sum[0] += a0.x; sum[1] += a0.y; sum[2] += a0.z; sum[3] += a0.w;
    sum[4] += a1.x; sum[5] += a1.y; sum[6] += a1.z; sum[7] += a1.w;
    half8 hv = *(const half8*)&Op[(((size_t)ch * 4 + b) * 256 + co) * 4096 + n8];
#pragma unroll
    for (int i = 0; i < 8; i++) o[i] += (float)hv[i];
  }
  float* op = out + ((size_t)b * 256 + co) * 4096 + n8;
  float4 r0, r1;
  r0.x = o[0] / sum[0]; r0.y = o[1] / sum[1]; r0.z = o[2] / sum[2]; r0.w = o[3] / sum[3];
  r1.x = o[4] / sum[4]; r1.y = o[5] / sum[5]; r1.z = o[6] / sum[6]; r1.w = o[7] / sum[7];
  *(float4*)op = r0;
  *(float4*)(op + 4) = r1;
}

extern "C" void kernel_launch(void* const* d_in, const int* in_sizes, int n_in,
                              void* d_out, int out_size, void* d_ws, size_t ws_size,
                              hipStream_t stream) {
  const float* rgb   = (const float*)d_in[0];
  const float* depth = (const float*)d_in[1];
  const float* Wq    = (const float*)d_in[2];
  const float* bq    = (const float*)d_in[3];
  const float* Wk    = (const float*)d_in[4];
  const float* bk    = (const float*)d_in[5];
  const float* Wv    = (const float*)d_in[6];
  const float* bv    = (const float*)d_in[7];
  float* out = (float*)d_out;

  unsigned short* qT = (unsigned short*)d_ws;             // 1 MB
  unsigned short* kT = qT + (size_t)4 * 4096 * 32;        // 1 MB
  unsigned short* vW = kT + (size_t)4 * 4096 * 32;        // 8 MB
  unsigned short* Op = vW + (size_t)4 * 256 * 4096;       // 33.5 MB
  float* lW = (float*)(Op + (size_t)4 * 4 * 256 * 4096);  // 256 KB

  dim3 pg(64, 4, 5);
  proj_kernel<<<pg, 256, 0, stream>>>(rgb, depth, Wq, bq, Wk, bk, Wv, bv, qT, kT, vW);
  dim3 ag(64, 4, 4);
  attn_kernel<<<ag, 256, 0, stream>>>(qT, kT, vW, Op, lW);
  dim3 cg(2, 4, 256);
  combine_kernel<<<cg, 256, 0, stream>>>(Op, lW, out);
}

// Round 8
// 198.381 us; speedup vs baseline: 1.3729x; 1.3729x over previous
//
#include <hip/hip_runtime.h>
#include <stdint.h>

#define L2E 1.44269504088896340736f

typedef _Float16 half8 __attribute__((ext_vector_type(8)));
typedef float floatx4 __attribute__((ext_vector_type(4)));
typedef float floatx16 __attribute__((ext_vector_type(16)));

static __device__ __forceinline__ unsigned short f32_to_f16u(float f) {
  union { _Float16 h; unsigned short s; } cv; cv.h = (_Float16)f; return cv.s;
}
static __device__ __forceinline__ _Float16 f32h(float f) { return (_Float16)f; }

// async global->LDS 16B, zero VGPR cost
static __device__ __forceinline__ void gld_lds16(const unsigned short* g, unsigned short* l) {
  __builtin_amdgcn_global_load_lds(
      (const __attribute__((address_space(1))) unsigned int*)g,
      (__attribute__((address_space(3))) unsigned int*)l, 16, 0, 0);
}

// ---------------------------------------------------------------------------
// Projection GEMM (unchanged from R7): X tile staged to LDS fp16 [256][74],
// W staged [64][256] swizzled; 64n x 64o per block.
// ---------------------------------------------------------------------------
__global__ __launch_bounds__(256, 2) void proj_kernel(
    const float* __restrict__ rgb,
    const float* __restrict__ depth,
    const float* __restrict__ Wq, const float* __restrict__ bq,
    const float* __restrict__ Wk, const float* __restrict__ bk,
    const float* __restrict__ Wv, const float* __restrict__ bv,
    unsigned short* __restrict__ qT,
    unsigned short* __restrict__ kT,
    unsigned short* __restrict__ v)
{
  __shared__ __align__(16) unsigned short sW[64 * 256];   // 32 KB, swizzled
  __shared__ __align__(16) unsigned short sX[256 * 74];   // 37.9 KB

  const int n0 = blockIdx.x * 64;
  const int b  = blockIdx.y;
  const int z  = blockIdx.z;
  const int t  = threadIdx.x;
  const int w  = t >> 6;
  const int lane = t & 63;
  const int l15 = lane & 15;
  const int q4  = lane >> 4;
  const int nl  = 16 * w + l15;

  const float* X = (z == 0) ? depth : rgb;
  const float* xb = X + (size_t)b * 256 * 4096 + n0;
  const int colbase = (z == 0) ? 0 : (z - 1) * 64;

#pragma unroll
  for (int it = 0; it < 8; it++) {
    int L = it * 256 + t;
    int og = L >> 5;
    int phys = L & 31;
    int ci = phys ^ (og & 7);
    const float* wr;
    if (z == 0) wr = (og < 32) ? (Wq + (size_t)og * 256) : (Wk + (size_t)(og - 32) * 256);
    else        wr = Wv + (size_t)(colbase + og) * 256;
    float4 w0 = *(const float4*)(wr + ci * 8);
    float4 w1 = *(const float4*)(wr + ci * 8 + 4);
    half8 h;
    h[0] = f32h(w0.x); h[1] = f32h(w0.y); h[2] = f32h(w0.z); h[3] = f32h(w0.w);
    h[4] = f32h(w1.x); h[5] = f32h(w1.y); h[6] = f32h(w1.z); h[7] = f32h(w1.w);
    *(half8*)&sW[(size_t)L * 8] = h;
  }

#pragma unroll
  for (int it = 0; it < 16; it++) {
    int c = it * 16 + (t >> 4);
    int nc = 4 * (t & 15);
    float4 x4 = *(const float4*)&xb[(size_t)c * 4096 + nc];
    ushort4 st;
    st.x = f32_to_f16u(x4.x); st.y = f32_to_f16u(x4.y);
    st.z = f32_to_f16u(x4.z); st.w = f32_to_f16u(x4.w);
    *(ushort4*)&sX[c * 74 + nc] = st;
  }

  float bias[4];
#pragma unroll
  for (int ct = 0; ct < 4; ct++) {
    int og = ct * 16 + l15;
    if (z == 0) bias[ct] = (og < 32) ? bq[og] : bk[og - 32];
    else        bias[ct] = bv[colbase + og];
  }
  __syncthreads();

  floatx4 acc[4];
#pragma unroll
  for (int i = 0; i < 4; i++) acc[i] = (floatx4){0.f, 0.f, 0.f, 0.f};

  const _Float16* sXh = (const _Float16*)sX;
#pragma unroll
  for (int ks = 0; ks < 8; ks++) {
    half8 a;
#pragma unroll
    for (int j = 0; j < 8; j++)
      a[j] = sXh[(ks * 32 + q4 * 8 + j) * 74 + nl];
    const int ci = ks * 4 + q4;
#pragma unroll
    for (int ct = 0; ct < 4; ct++) {
      int og = ct * 16 + l15;
      half8 bf = *(const half8*)&sW[og * 256 + ((ci ^ (og & 7)) * 8)];
      acc[ct] = __builtin_amdgcn_mfma_f32_16x16x32_f16(a, bf, acc[ct], 0, 0, 0);
    }
  }

  __syncthreads();

  if (z == 0) {
#pragma unroll
    for (int ct = 0; ct < 4; ct++) {
      int og = ct * 16 + l15;
#pragma unroll
      for (int r = 0; r < 4; r++) {
        int n = n0 + 16 * w + q4 * 4 + r;
        unsigned short hv = f32_to_f16u(acc[ct][r] + bias[ct]);
        if (og < 32) qT[((size_t)b * 4096 + n) * 32 + og] = hv;
        else         kT[((size_t)b * 4096 + n) * 32 + (og - 32)] = hv;
      }
    }
  } else {
    unsigned short* tile = sW;
#pragma unroll
    for (int ct = 0; ct < 4; ct++) {
#pragma unroll
      for (int r = 0; r < 4; r++) {
        int co_l = ct * 16 + l15;
        int nn = 16 * w + q4 * 4 + r;
        tile[co_l * 72 + nn] = f32_to_f16u(acc[ct][r] + bias[ct]);
      }
    }
    __syncthreads();
#pragma unroll
    for (int it = 0; it < 2; it++) {
      int co_l = it * 32 + (t >> 3);
      int ch = t & 7;
      int4 val = *(const int4*)&tile[co_l * 72 + ch * 8];
      *(int4*)&v[((size_t)b * 256 + colbase + co_l) * 4096 + n0 + ch * 8] = val;
    }
  }
}

// ---------------------------------------------------------------------------
// Flash attention v3: block = (128 n, b, m-chunk 1024), 4 waves, 2 blocks/CU.
// Wave-tile: 64 co x 128 n (acc 4x2 floatx16 = 128 VGPR).
// V staged async via global_load_lds into double buffer (zero VGPR);
// K direct-to-reg double-buffered. 2 barriers/iter.
// ---------------------------------------------------------------------------
__global__ __launch_bounds__(256, 2) void attn_kernel(
    const unsigned short* __restrict__ qT,  // [b][n][32] fp16
    const unsigned short* __restrict__ kT,  // [b][m][32] fp16
    const unsigned short* __restrict__ v,   // [b][co][m] fp16
    unsigned short* __restrict__ Op,        // [chunk][b][co][n] fp16 unnormalized
    float* __restrict__ lW)                 // [chunk][b][n]
{
  __shared__ __align__(16) unsigned char smem[43520];
  unsigned short* sVb = (unsigned short*)smem;             // 2 x [256co][32m] swizzled (2x16384B)
  unsigned short* sP  = (unsigned short*)(smem + 32768);   // [128n][pitch 42] (10752B)

  const int n0 = blockIdx.x * 128;
  const int b  = blockIdx.y;
  const int chunk = blockIdx.z;
  const int t  = threadIdx.x;
  const int w  = t >> 6;
  const int lane = t & 63;
  const int l15 = lane & 15;
  const int q4  = lane >> 4;
  const int l31 = lane & 31;
  const int hi  = lane >> 5;

  // Q A-frags: S rows n0 + w*32 + g*16 + l15
  half8 aq[2];
#pragma unroll
  for (int g = 0; g < 2; g++)
    aq[g] = *(const half8*)&qT[((size_t)b * 4096 + n0 + w * 32 + g * 16 + l15) * 32 + q4 * 8];

  const unsigned short* vB = v  + (size_t)b * 256 * 4096;
  const unsigned short* kB = kT + (size_t)b * 4096 * 32;
  const int mbase = chunk * 1024;

  float lsum[2][4];
#pragma unroll
  for (int g = 0; g < 2; g++)
#pragma unroll
    for (int r = 0; r < 4; r++) lsum[g][r] = 0.f;

  floatx16 acc[4][2];  // [nt: n=nt*32+..][ct: co=w*64+ct*32+..]
#pragma unroll
  for (int nt = 0; nt < 4; nt++)
#pragma unroll
    for (int ct = 0; ct < 2; ct++)
#pragma unroll
      for (int i = 0; i < 16; i++) acc[nt][ct][i] = 0.f;
  const floatx4 zf = (floatx4){0.f, 0.f, 0.f, 0.f};

  // preamble: async V tile 0 -> buf 0; K frags for tile 0
#pragma unroll
  for (int j = 0; j < 4; j++) {
    int lin = j * 256 + t;
    int c = lin >> 2;
    int p = lin & 3;
    int lc = p ^ ((c >> 1) & 3);
    gld_lds16(&vB[(size_t)c * 4096 + mbase + lc * 8], &sVb[lin * 8]);
  }
  half8 bkc0 = *(const half8*)&kB[(size_t)(mbase + l15) * 32 + q4 * 8];
  half8 bkc1 = *(const half8*)&kB[(size_t)(mbase + 16 + l15) * 32 + q4 * 8];

  int buf = 0;
  for (int mi = 0; mi < 1024; mi += 32) {
    // ---- S phase: wave w computes rows w*32 .. w*32+31
    floatx4 s0[2], s1[2];
#pragma unroll
    for (int g = 0; g < 2; g++) {
      s0[g] = __builtin_amdgcn_mfma_f32_16x16x32_f16(aq[g], bkc0, zf, 0, 0, 0);
      s1[g] = __builtin_amdgcn_mfma_f32_16x16x32_f16(aq[g], bkc1, zf, 0, 0, 0);
    }
#pragma unroll
    for (int g = 0; g < 2; g++) {
#pragma unroll
      for (int r = 0; r < 4; r++) {
        float p0 = exp2f(s0[g][r] * L2E);
        float p1 = exp2f(s1[g][r] * L2E);
        lsum[g][r] += p0 + p1;
        int row = w * 32 + g * 16 + q4 * 4 + r;
        sP[row * 42 + l15]      = f32_to_f16u(p0);
        sP[row * 42 + 16 + l15] = f32_to_f16u(p1);
      }
    }
    asm volatile("s_waitcnt vmcnt(0)" ::: "memory");  // sV[buf] ready (iter0: preamble)
    __syncthreads();  // C: sP + sV[buf] visible

    // ---- issue next-tile async V + next K (hidden under PV)
    if (mi < 992) {
      const int m0n = mbase + mi + 32;
      unsigned short* sVn = sVb + (buf ^ 1) * 8192;
#pragma unroll
      for (int j = 0; j < 4; j++) {
        int lin = j * 256 + t;
        int c = lin >> 2;
        int p = lin & 3;
        int lc = p ^ ((c >> 1) & 3);
        gld_lds16(&vB[(size_t)c * 4096 + m0n + lc * 8], &sVn[lin * 8]);
      }
      bkc0 = *(const half8*)&kB[(size_t)(m0n + l15) * 32 + q4 * 8];
      bkc1 = *(const half8*)&kB[(size_t)(m0n + 16 + l15) * 32 + q4 * 8];
    }

    // ---- PV phase: wave w covers co = w*64..w*64+63, all 128 n
    const unsigned short* sV = sVb + buf * 8192;
#pragma unroll
    for (int kst = 0; kst < 2; kst++) {
      half8 bvv[2];
#pragma unroll
      for (int ct = 0; ct < 2; ct++) {
        int co = w * 64 + ct * 32 + l31;
        int lc = (kst * 2 + hi) ^ ((co >> 1) & 3);
        bvv[ct] = *(const half8*)&sV[(co * 4 + lc) * 8];
      }
#pragma unroll
      for (int nt = 0; nt < 4; nt++) {
        half8 ap = *(const half8*)&sP[(nt * 32 + l31) * 42 + kst * 16 + hi * 8];
#pragma unroll
        for (int ct = 0; ct < 2; ct++)
          acc[nt][ct] = __builtin_amdgcn_mfma_f32_32x32x16_f16(ap, bvv[ct], acc[nt][ct], 0, 0, 0);
      }
    }
    asm volatile("s_waitcnt vmcnt(0)" ::: "memory");  // next-tile async complete
    __syncthreads();  // E: PV reads done; next iter may overwrite sP / sV[buf^1] ready
    buf ^= 1;
  }

  // ---- l reduction (rows w*32+g*16+q4*4+r; sum over 16 lanes l15)
#pragma unroll
  for (int off = 1; off < 16; off <<= 1) {
#pragma unroll
    for (int g = 0; g < 2; g++)
#pragma unroll
      for (int r = 0; r < 4; r++) lsum[g][r] += __shfl_xor(lsum[g][r], off);
  }
  if (l15 == 0) {
#pragma unroll
    for (int g = 0; g < 2; g++)
#pragma unroll
      for (int r = 0; r < 4; r++)
        lW[((size_t)chunk * 4 + b) * 4096 + n0 + w * 32 + g * 16 + q4 * 4 + r] = lsum[g][r];
  }

  // ---- epilogue: two passes of 128 co, [128][pitch 136] fp16 = 34816 B
  unsigned short* sO = (unsigned short*)smem;
#pragma unroll
  for (int pass = 0; pass < 2; pass++) {
    __syncthreads();
    if ((w >> 1) == pass) {
      const int co_l = (w & 1) * 64 + 0;  // base; ct/l31 below
#pragma unroll
      for (int nt = 0; nt < 4; nt++) {
#pragma unroll
        for (int ct = 0; ct < 2; ct++) {
          int cl = (w & 1) * 64 + ct * 32 + l31;
#pragma unroll
          for (int g = 0; g < 4; g++) {
            int nn = nt * 32 + g * 8 + hi * 4;
            ushort4 pk;
            pk.x = f32_to_f16u(acc[nt][ct][g * 4 + 0]);
            pk.y = f32_to_f16u(acc[nt][ct][g * 4 + 1]);
            pk.z = f32_to_f16u(acc[nt][ct][g * 4 + 2]);
            pk.w = f32_to_f16u(acc[nt][ct][g * 4 + 3]);
            *(ushort4*)&sO[cl * 136 + nn] = pk;
          }
        }
      }
      (void)co_l;
    }
    __syncthreads();
#pragma unroll
    for (int it = 0; it < 8; it++) {
      int cl = it * 16 + (t >> 4);
      int ch = t & 15;
      int4 val = *(const int4*)&sO[cl * 136 + ch * 8];
      *(int4*)&Op[(((size_t)chunk * 4 + b) * 256 + pass * 128 + cl) * 4096 + n0 + ch * 8] = val;
    }
  }
}

// ---------------------------------------------------------------------------
// Combine: out[b][co][n] = sum_ch Op[ch][b][co][n] / sum_ch lW[ch][b][n]
// ---------------------------------------------------------------------------
__global__ __launch_bounds__(256) void combine_kernel(
    const unsigned short* __restrict__ Op,
    const float* __restrict__ lW,
    float* __restrict__ out)
{
  const int t = threadIdx.x;
  const int b = blockIdx.y;
  const int co = blockIdx.z;
  const size_t n8 = (size_t)blockIdx.x * 2048 + (size_t)t * 8;

  float sum[8] = {0.f, 0.f, 0.f, 0.f, 0.f, 0.f, 0.f, 0.f};
  float o[8]   = {0.f, 0.f, 0.f, 0.f, 0.f, 0.f, 0.f, 0.f};
#pragma unroll
  for (int ch = 0; ch < 4; ch++) {
    const float* lp = lW + ((size_t)ch * 4 + b) * 4096 + n8;
    float4 a0 = *(const float4*)lp;
    float4 a1 = *(const float4*)(lp + 4);
    sum[0] += a0.x; sum[1] += a0.y; sum[2] += a0.z; sum[3] += a0.w;
    sum[4] += a1.x; sum[5] += a1.y; sum[6] += a1.z; sum[7] += a1.w;
    half8 hv = *(const half8*)&Op[(((size_t)ch * 4 + b) * 256 + co) * 4096 + n8];
#pragma unroll
    for (int i = 0; i < 8; i++) o[i] += (float)hv[i];
  }
  float* op = out + ((size_t)b * 256 + co) * 4096 + n8;
  float4 r0, r1;
  r0.x = o[0] / sum[0]; r0.y = o[1] / sum[1]; r0.z = o[2] / sum[2]; r0.w = o[3] / sum[3];
  r1.x = o[4] / sum[4]; r1.y = o[5] / sum[5]; r1.z = o[6] / sum[6]; r1.w = o[7] / sum[7];
  *(float4*)op = r0;
  *(float4*)(op + 4) = r1;
}

extern "C" void kernel_launch(void* const* d_in, const int* in_sizes, int n_in,
                              void* d_out, int out_size, void* d_ws, size_t ws_size,
                              hipStream_t stream) {
  const float* rgb   = (const float*)d_in[0];
  const float* depth = (const float*)d_in[1];
  const float* Wq    = (const float*)d_in[2];
  const float* bq    = (const float*)d_in[3];
  const float* Wk    = (const float*)d_in[4];
  const float* bk    = (const float*)d_in[5];
  const float* Wv    = (const float*)d_in[6];
  const float* bv    = (const float*)d_in[7];
  float* out = (float*)d_out;

  unsigned short* qT = (unsigned short*)d_ws;             // 1 MB
  unsigned short* kT = qT + (size_t)4 * 4096 * 32;        // 1 MB
  unsigned short* vW = kT + (size_t)4 * 4096 * 32;        // 8 MB
  unsigned short* Op = vW + (size_t)4 * 256 * 4096;       // 33.5 MB
  float* lW = (float*)(Op + (size_t)4 * 4 * 256 * 4096);  // 256 KB

  dim3 pg(64, 4, 5);
  proj_kernel<<<pg, 256, 0, stream>>>(rgb, depth, Wq, bq, Wk, bk, Wv, bv, qT, kT, vW);
  dim3 ag(32, 4, 4);
  attn_kernel<<<ag, 256, 0, stream>>>(qT, kT, vW, Op, lW);
  dim3 cg(2, 4, 256);
  combine_kernel<<<cg, 256, 0, stream>>>(Op, lW, out);
}